// Round 11
// baseline (126.633 us; speedup 1.0000x reference)
//
#include <hip/hip_runtime.h>
#include <math.h>

typedef _Float16 f16x2 __attribute__((ext_vector_type(2)));

namespace {
constexpr int DIN = 36, DOUT = 34;
constexpr int TDD = 2, TE = 8, TF = 8;       // site tile (d,e,f) = (2,8,8) = 128 sites
constexpr int RD = 4, RE = 10, RF = 10;      // staged region rows
constexpr int NROWS = RD*RE*RF;              // 400 rows
constexpr int ROWD  = 19;                    // dwords per row per plane (18 data + 1 pad), ODD stride
constexpr int PLANE = NROWS*ROWD;            // 7600 dwords per channel plane
constexpr int NCHUNK = NROWS*9;              // 3600 16-B source chunks
constexpr int NBD = 17, NBE = 5, NBF = 5;
constexpr int BLOCKS_PER_B = NBD*NBE*NBF;    // 425
constexpr int NBLOCKS = 8*BLOCKS_PER_B;      // 3400 = 8 XCDs x 425
constexpr int NT = 512;
constexpr int SITER = (NCHUNK + NT - 1)/NT;  // 8
constexpr int D3 = DIN*DIN*DIN, D2 = DIN*DIN;
}

__device__ __forceinline__ unsigned div9u(unsigned n)   { return __umulhi(n, 0x38E38E39u) >> 1; }
__device__ __forceinline__ unsigned div100u(unsigned n) { return __umulhi(n, 0x51EB851Fu) >> 5; }
__device__ __forceinline__ unsigned div10u(unsigned n)  { return __umulhi(n, 0x66666667u) >> 2; }

__device__ __forceinline__ f16x2 bch(unsigned u) { union { unsigned u; f16x2 h; } x; x.u = u; return x.h; }
__device__ __forceinline__ unsigned pack2h(float a, float b) {
    union { f16x2 h; unsigned u; } x; x.h = f16x2{(_Float16)a, (_Float16)b}; return x.u;
}

// Coalesced stage of both channels into separate fp16 planes.
// Chunk C: row C/9, 4 floats at chunk C%9 -> 2 packed dwords at row*ROWD + 2c.
__device__ __forceinline__ void stage(const float* __restrict__ xr, const float* __restrict__ xi,
                                      unsigned* __restrict__ s_xu, int t, unsigned g0off)
{
    #pragma unroll
    for (int it = 0; it < SITER; ++it) {
        const int C = it*NT + t;
        if (C < NCHUNK) {
            const unsigned row = div9u((unsigned)C);
            const unsigned c   = (unsigned)C - row*9u;
            const unsigned rd  = div100u(row);
            const unsigned rem = row - rd*100u;
            const unsigned re  = div10u(rem);
            const unsigned rf  = rem - re*10u;
            const unsigned goff = g0off + rd*D3 + re*D2 + rf*DIN + c*4u;
            const float4 vr = *reinterpret_cast<const float4*>(xr + goff);
            const float4 vi = *reinterpret_cast<const float4*>(xi + goff);
            unsigned* dst = s_xu + row*ROWD + c*2u;
            dst[0]         = pack2h(vr.x, vr.y);
            dst[1]         = pack2h(vr.z, vr.w);
            dst[PLANE]     = pack2h(vi.x, vi.y);
            dst[PLANE + 1] = pack2h(vi.z, vi.w);
        }
    }
}

// One w-group's conv + epilogue. Packed fp16 accumulators over w-pairs.
// All register indices compile-time after unrolling (no scratch demotion).
template<int NW, int W0>
__device__ __forceinline__ float conv_group(const unsigned* __restrict__ s_xu,
                                            const uint4* __restrict__ s_wA,
                                            const uint4* __restrict__ s_wB,
                                            const uint4* __restrict__ s_wC,
                                            int td, int e, int f,
                                            const float* __restrict__ s_hw,
                                            float c_br, float c_bi, float hinit)
{
    constexpr int P  = NW/2;                 // w-pairs: 5 or 4
    constexpr int WD = W0/2;                 // dword base within row
    f16x2 yr[P], yi[P];
    #pragma unroll
    for (int p = 0; p < P; ++p) { yr[p] = f16x2{0.f, 0.f}; yi[p] = f16x2{0.f, 0.f}; }

    const int rbase = td*(RE*RF) + e*RF + f;

    #pragma unroll 1
    for (int i = 0; i < 3; ++i)
    #pragma unroll 1
    for (int j = 0; j < 3; ++j)
    {
        const unsigned* pr  = s_xu + (rbase + i*(RE*RF) + j*RF)*ROWD + WD;
        const unsigned* pim = pr + PLANE;
        const int tapb = (i*3 + j)*3;
        #pragma unroll
        for (int k = 0; k < 3; ++k)          // k*ROWD*4 folds into ds offsets
        {
            unsigned dr[P+2], di[P+2];
            #pragma unroll
            for (int m = 0; m < P+2; ++m) { dr[m] = pr[k*ROWD + m]; di[m] = pim[k*ROWD + m]; }

            const uint4 wa = s_wA[tapb + k];  // (wr,wr) per l   (broadcast reads)
            const uint4 wb = s_wB[tapb + k];  // (-wi,-wi)
            const uint4 wc = s_wC[tapb + k];  // (wi,wi)
            #pragma unroll
            for (int l = 0; l < 3; ++l) {
                const f16x2 WA = bch(l==0 ? wa.x : l==1 ? wa.y : wa.z);
                const f16x2 WB = bch(l==0 ? wb.x : l==1 ? wb.y : wb.z);
                const f16x2 WC = bch(l==0 ? wc.x : l==1 ? wc.y : wc.z);
                #pragma unroll
                for (int p = 0; p < P; ++p) {
                    const f16x2 xrp = (l==0) ? bch(dr[p])
                                    : (l==1) ? bch(__builtin_amdgcn_alignbit(dr[p+1], dr[p], 16))
                                             : bch(dr[p+1]);
                    const f16x2 xip = (l==0) ? bch(di[p])
                                    : (l==1) ? bch(__builtin_amdgcn_alignbit(di[p+1], di[p], 16))
                                             : bch(di[p+1]);
                    yr[p] += xrp * WA;        // v_pk_fma_f16
                    yr[p] += xip * WB;
                    yi[p] += xrp * WC;
                    yi[p] += xip * WA;
                }
            }
        }
    }

    // fp32 epilogue: bias -> CReLU -> modulus -> head partial
    float h = hinit;
    #pragma unroll
    for (int p = 0; p < P; ++p) {
        {
            const float a = fmaxf((float)yr[p].x + c_br, 0.f);
            const float c = fmaxf((float)yi[p].x + c_bi, 0.f);
            const float m = sqrtf(fmaf(a, a, fmaf(c, c, 1e-12f)));
            h = fmaf(m, s_hw[W0 + 2*p], h);
        }
        {
            const float a = fmaxf((float)yr[p].y + c_br, 0.f);
            const float c = fmaxf((float)yi[p].y + c_bi, 0.f);
            const float m = sqrtf(fmaf(a, a, fmaf(c, c, 1e-12f)));
            h = fmaf(m, s_hw[W0 + 2*p + 1], h);
        }
    }
    return h;
}

__global__ __launch_bounds__(NT)
void lasl_kernel(const float* __restrict__ xr, const float* __restrict__ xi,
                 const float* __restrict__ wr, const float* __restrict__ wi,
                 const float* __restrict__ br, const float* __restrict__ bi,
                 const float* __restrict__ hw, const float* __restrict__ hb,
                 float* __restrict__ out)
{
    __shared__ unsigned s_xu[2*PLANE];           // 60.8 KB: xr plane, xi plane
    __shared__ uint4 s_wA[27], s_wB[27], s_wC[27];
    __shared__ float s_hw[DOUT], s_scal[3];

    const int t = threadIdx.x;
    if (t < 27) {
        const float w0r = wr[3*t], w1r = wr[3*t+1], w2r = wr[3*t+2];
        const float w0i = wi[3*t], w1i = wi[3*t+1], w2i = wi[3*t+2];
        s_wA[t] = make_uint4(pack2h(w0r, w0r),  pack2h(w1r, w1r),  pack2h(w2r, w2r),  0u);
        s_wB[t] = make_uint4(pack2h(-w0i,-w0i), pack2h(-w1i,-w1i), pack2h(-w2i,-w2i), 0u);
        s_wC[t] = make_uint4(pack2h(w0i, w0i),  pack2h(w1i, w1i),  pack2h(w2i, w2i),  0u);
    } else if (t >= 32 && t < 32 + DOUT) {
        s_hw[t-32] = hw[t-32];
    } else if (t == 96) { s_scal[0] = br[0]; s_scal[1] = bi[0]; s_scal[2] = hb[0]; }

    // batch-per-XCD bijective swizzle: 3400 = 8 * 425
    const int bid = blockIdx.x;
    const int b   = bid & 7;
    int rem = bid >> 3;                          // 0..424
    const int d0 = (rem / 25) * TDD;  rem %= 25; // exact: 17*2 = 34
    const int e0 = min((rem / 5) * TE, DOUT - TE);  // overlap tiles: duplicate outputs
    const int f0 = min((rem % 5) * TF, DOUT - TF);  // write identical values

    const float* xrb = xr + (size_t)b * (size_t)(DIN*D3);
    const float* xib = xi + (size_t)b * (size_t)(DIN*D3);
    const unsigned g0off = (unsigned)((d0*DIN + e0)*DIN + f0)*DIN;

    stage(xrb, xib, s_xu, t, g0off);
    __syncthreads();

    const int f  = t & 7;                        // site within tile
    const int e  = (t >> 3) & 7;
    const int g  = (t >> 6) & 3;                 // wave-uniform w-group (4 groups)
    const int td = t >> 8;                       // wave-uniform d-sub

    const float c_br = s_scal[0], c_bi = s_scal[1];
    const float hini = (g == 0) ? s_scal[2] : 0.f;   // hb counted once

    float hp;
    if      (g == 0) hp = conv_group<10, 0>(s_xu, s_wA, s_wB, s_wC, td, e, f, s_hw, c_br, c_bi, hini);
    else if (g == 1) hp = conv_group< 8,10>(s_xu, s_wA, s_wB, s_wC, td, e, f, s_hw, c_br, c_bi, hini);
    else if (g == 2) hp = conv_group< 8,18>(s_xu, s_wA, s_wB, s_wC, td, e, f, s_hw, c_br, c_bi, hini);
    else             hp = conv_group< 8,26>(s_xu, s_wA, s_wB, s_wC, td, e, f, s_hw, c_br, c_bi, hini);

    // combine the 4 w-group partials (one per wave, same td) through LDS
    __syncthreads();                             // all s_xu reads done
    float* s_red = reinterpret_cast<float*>(s_xu);
    s_red[t] = hp;
    __syncthreads();

    if (g == 0) {
        const int eg = e0 + e, fg = f0 + f;      // always < 34 (overlap tiling)
        const float htot = hp + s_red[t + 64] + s_red[t + 128] + s_red[t + 192];
        out[(((size_t)b*DOUT + (d0 + td))*DOUT + eg)*DOUT + fg] = 1.f / (1.f + __expf(-htot));
    }
}

extern "C" void kernel_launch(void* const* d_in, const int* in_sizes, int n_in,
                              void* d_out, int out_size, void* d_ws, size_t ws_size,
                              hipStream_t stream)
{
    const float* xr = (const float*)d_in[0];
    const float* xi = (const float*)d_in[1];
    const float* wr = (const float*)d_in[2];
    const float* wi = (const float*)d_in[3];
    const float* br = (const float*)d_in[4];
    const float* bi = (const float*)d_in[5];
    const float* hw = (const float*)d_in[6];
    const float* hb = (const float*)d_in[7];
    float* out = (float*)d_out;

    lasl_kernel<<<NBLOCKS, NT, 0, stream>>>(xr, xi, wr, wi, br, bi, hw, hb, out);
}

// Round 12
// 114.223 us; speedup vs baseline: 1.1086x; 1.1086x over previous
//
#include <hip/hip_runtime.h>
#include <hip/hip_fp16.h>
#include <math.h>

namespace {
constexpr int DIN = 36, DOUT = 34;
constexpr int TDD = 2, TE = 8, TF = 8;       // site tile (d,e,f) = (2,8,8) = 128 sites
constexpr int RD = 4, RE = 10, RF = 10;      // staged region rows
constexpr int NROWS = RD*RE*RF;              // 400 rows
constexpr int ROWW  = 38;                    // dwords/row (36 data + 2 pad) = 152 B
constexpr int NCHUNK = NROWS*9;              // 3600 16-B source chunks
constexpr int NBD = 17, NBE = 5, NBF = 5;
constexpr int BLOCKS_PER_B = NBD*NBE*NBF;    // 425
constexpr int NBLOCKS = 8*BLOCKS_PER_B;      // 3400 = 8 XCDs x 425
constexpr int NT = 512;
constexpr int SITER = (NCHUNK + NT - 1)/NT;  // 8
constexpr int D3 = DIN*DIN*DIN, D2 = DIN*DIN;
}

__device__ __forceinline__ unsigned div9u(unsigned n)   { return __umulhi(n, 0x38E38E39u) >> 1; }
__device__ __forceinline__ unsigned div100u(unsigned n) { return __umulhi(n, 0x51EB851Fu) >> 5; }
__device__ __forceinline__ unsigned div10u(unsigned n)  { return __umulhi(n, 0x66666667u) >> 2; }

__device__ __forceinline__ unsigned pack2h(float a, float b) {
    union { __half2 h; unsigned u; } x; x.h = __floats2half2_rn(a, b); return x.u;
}
__device__ __forceinline__ __half2 bch(unsigned u) {
    union { unsigned u; __half2 h; } x; x.u = u; return x.h;
}

// Coalesced stage of both channels, interleaved (xr,xi) half2 per dword.
// Chunk C: row C/9, 4 floats at chunk C%9. 8B-aligned uint2 LDS writes.
__device__ __forceinline__ void stage(const float* __restrict__ xr, const float* __restrict__ xi,
                                      unsigned* __restrict__ s_xu, int t, unsigned g0off)
{
    #pragma unroll
    for (int it = 0; it < SITER; ++it) {
        const int C = it*NT + t;
        if (C < NCHUNK) {
            const unsigned row = div9u((unsigned)C);
            const unsigned c   = (unsigned)C - row*9u;
            const unsigned rd  = div100u(row);
            const unsigned rem = row - rd*100u;
            const unsigned re  = div10u(rem);
            const unsigned rf  = rem - re*10u;
            const unsigned goff = g0off + rd*D3 + re*D2 + rf*DIN + c*4u;
            const float4 vr = *reinterpret_cast<const float4*>(xr + goff);
            const float4 vi = *reinterpret_cast<const float4*>(xi + goff);
            unsigned* dst = s_xu + row*ROWW + c*4;
            uint2 lo, hi;
            lo.x = pack2h(vr.x, vi.x); lo.y = pack2h(vr.y, vi.y);
            hi.x = pack2h(vr.z, vi.z); hi.y = pack2h(vr.w, vi.w);
            *reinterpret_cast<uint2*>(dst)     = lo;
            *reinterpret_cast<uint2*>(dst + 2) = hi;
        }
    }
}

// One w-group's conv + epilogue. Full-rate v_pk_fma_f16: the f16x2 accumulator
// halves carry the two channel terms; summed once in the fp32 epilogue.
// All register indices compile-time (no scratch demotion).
template<int NW, int W0>
__device__ __forceinline__ float conv_group(const unsigned* __restrict__ s_xu,
                                            const uint4* __restrict__ s_wA,
                                            const uint4* __restrict__ s_wB,
                                            int td, int e, int f,
                                            const float* __restrict__ s_hw,
                                            float c_br, float c_bi, float hinit)
{
    constexpr int NL = NW/2 + 1;                 // b64 loads per row-window
    __half2 accr[NW], acci[NW];
    #pragma unroll
    for (int w = 0; w < NW; ++w) {
        accr[w] = __floats2half2_rn(0.f, 0.f);
        acci[w] = __floats2half2_rn(0.f, 0.f);
    }

    const int abase = (td*(RE*RF) + e*RF + f)*ROWW + W0;   // even dword -> 8B aligned

    #pragma unroll 1
    for (int i = 0; i < 3; ++i)
    #pragma unroll 1
    for (int j = 0; j < 3; ++j)
    {
        const unsigned* sp = s_xu + abase + (i*(RE*RF) + j*RF)*ROWW;
        const int tapb = (i*3 + j)*3;
        #pragma unroll
        for (int k = 0; k < 3; ++k)              // k*ROWW*4 folds into ds offsets
        {
            uint2 q[NL];
            #pragma unroll
            for (int m = 0; m < NL; ++m)
                q[m] = *reinterpret_cast<const uint2*>(sp + k*ROWW + 2*m);
            const __half2* win = reinterpret_cast<const __half2*>(q);

            const uint4 wa = s_wA[tapb + k];     // (wr, -wi) per l  (broadcast)
            const uint4 wb = s_wB[tapb + k];     // (wi,  wr) per l
            #pragma unroll
            for (int l = 0; l < 3; ++l) {
                const __half2 WA = bch(l==0 ? wa.x : l==1 ? wa.y : wa.z);
                const __half2 WB = bch(l==0 ? wb.x : l==1 ? wb.y : wb.z);
                #pragma unroll
                for (int w = 0; w < NW; ++w) {
                    const __half2 x2 = win[w + l];          // (xr, xi)
                    accr[w] = __hfma2(x2, WA, accr[w]);     // (xr*wr, -xi*wi)
                    acci[w] = __hfma2(x2, WB, acci[w]);     // (xr*wi,  xi*wr)
                }
            }
        }
    }

    // fp32 epilogue: sum halves -> bias -> CReLU -> modulus -> head partial
    float h = hinit;
    #pragma unroll
    for (int w = 0; w < NW; ++w) {
        const float yr = __low2float(accr[w]) + __high2float(accr[w]) + c_br;
        const float yi = __low2float(acci[w]) + __high2float(acci[w]) + c_bi;
        const float a = fmaxf(yr, 0.f);
        const float c = fmaxf(yi, 0.f);
        const float m = sqrtf(fmaf(a, a, fmaf(c, c, 1e-12f)));
        h = fmaf(m, s_hw[W0 + w], h);
    }
    return h;
}

__global__ __launch_bounds__(NT)
void lasl_kernel(const float* __restrict__ xr, const float* __restrict__ xi,
                 const float* __restrict__ wr, const float* __restrict__ wi,
                 const float* __restrict__ br, const float* __restrict__ bi,
                 const float* __restrict__ hw, const float* __restrict__ hb,
                 float* __restrict__ out)
{
    __shared__ unsigned s_xu[NROWS*ROWW];        // 60.8 KB interleaved fp16 tile
    __shared__ uint4 s_wA[27], s_wB[27];
    __shared__ float s_hw[DOUT], s_scal[3];

    const int t = threadIdx.x;
    if (t < 27) {
        const float w0r = wr[3*t], w1r = wr[3*t+1], w2r = wr[3*t+2];
        const float w0i = wi[3*t], w1i = wi[3*t+1], w2i = wi[3*t+2];
        s_wA[t] = make_uint4(pack2h(w0r, -w0i), pack2h(w1r, -w1i), pack2h(w2r, -w2i), 0u);
        s_wB[t] = make_uint4(pack2h(w0i,  w0r), pack2h(w1i,  w1r), pack2h(w2i,  w2r), 0u);
    } else if (t >= 32 && t < 32 + DOUT) {
        s_hw[t-32] = hw[t-32];
    } else if (t == 96) { s_scal[0] = br[0]; s_scal[1] = bi[0]; s_scal[2] = hb[0]; }

    // batch-per-XCD bijective swizzle: 3400 = 8 * 425
    const int bid = blockIdx.x;
    const int b   = bid & 7;
    int rem = bid >> 3;                          // 0..424
    const int d0 = (rem / 25) * TDD;  rem %= 25; // exact: 17*2 = 34
    const int e0 = min((rem / 5) * TE, DOUT - TE);  // overlap tiles: duplicate outputs
    const int f0 = min((rem % 5) * TF, DOUT - TF);  // write identical values

    const float* xrb = xr + (size_t)b * (size_t)(DIN*D3);
    const float* xib = xi + (size_t)b * (size_t)(DIN*D3);
    const unsigned g0off = (unsigned)((d0*DIN + e0)*DIN + f0)*DIN;

    stage(xrb, xib, s_xu, t, g0off);
    __syncthreads();

    const int f  = t & 7;                        // site within tile
    const int e  = (t >> 3) & 7;
    const int g  = (t >> 6) & 3;                 // wave-uniform w-group (4 groups)
    const int td = t >> 8;                       // wave-uniform d-sub

    const float c_br = s_scal[0], c_bi = s_scal[1];
    const float hini = (g == 0) ? s_scal[2] : 0.f;   // hb counted once

    float hp;
    if      (g == 0) hp = conv_group<10, 0>(s_xu, s_wA, s_wB, td, e, f, s_hw, c_br, c_bi, hini);
    else if (g == 1) hp = conv_group< 8,10>(s_xu, s_wA, s_wB, td, e, f, s_hw, c_br, c_bi, hini);
    else if (g == 2) hp = conv_group< 8,18>(s_xu, s_wA, s_wB, td, e, f, s_hw, c_br, c_bi, hini);
    else             hp = conv_group< 8,26>(s_xu, s_wA, s_wB, td, e, f, s_hw, c_br, c_bi, hini);

    // combine the 4 w-group partials (one per wave, same td) through LDS
    __syncthreads();                             // all s_xu reads done
    float* s_red = reinterpret_cast<float*>(s_xu);
    s_red[t] = hp;
    __syncthreads();

    if (g == 0) {
        const int eg = e0 + e, fg = f0 + f;      // always < 34 (overlap tiling)
        const float htot = hp + s_red[t + 64] + s_red[t + 128] + s_red[t + 192];
        out[(((size_t)b*DOUT + (d0 + td))*DOUT + eg)*DOUT + fg] = 1.f / (1.f + __expf(-htot));
    }
}

extern "C" void kernel_launch(void* const* d_in, const int* in_sizes, int n_in,
                              void* d_out, int out_size, void* d_ws, size_t ws_size,
                              hipStream_t stream)
{
    const float* xr = (const float*)d_in[0];
    const float* xi = (const float*)d_in[1];
    const float* wr = (const float*)d_in[2];
    const float* wi = (const float*)d_in[3];
    const float* br = (const float*)d_in[4];
    const float* bi = (const float*)d_in[5];
    const float* hw = (const float*)d_in[6];
    const float* hb = (const float*)d_in[7];
    float* out = (float*)d_out;

    lasl_kernel<<<NBLOCKS, NT, 0, stream>>>(xr, xi, wr, wi, br, bi, hw, hb, out);
}

// Round 13
// 108.150 us; speedup vs baseline: 1.1709x; 1.0562x over previous
//
#include <hip/hip_runtime.h>
#include <hip/hip_fp16.h>
#include <math.h>

namespace {
constexpr int DIN = 36, DOUT = 34;
constexpr int TE = 8, TF = 8;                // site tile (d,e,f) = (1,8,8) = 64 sites
constexpr int RE = 10, RF = 10;              // staged region: 3 x 10 x 10 rows
constexpr int NROWS = 3*RE*RF;               // 300 rows
constexpr int ROWW  = 38;                    // dwords/row (36 data + 2 pad) = 152 B
constexpr int NCHUNK = NROWS*9;              // 2700 16-B source chunks
constexpr int BLOCKS_PER_B = 34*5*5;         // 850
constexpr int NBLOCKS = 8*BLOCKS_PER_B;      // 6800 = 8 XCDs x 850
constexpr int NT = 512;                      // 8 waves: wave g owns w-group g, lane = site
constexpr int SITER = (NCHUNK + NT - 1)/NT;  // 6
constexpr int D3 = DIN*DIN*DIN, D2 = DIN*DIN;
// d_ws dword layout (written by prep_kernel, read via uniform/scalar loads)
constexpr int WS_WPK  = 0;                   // 27 taps x 2 uint4 = 216 dwords
constexpr int WS_SCAL = 216;                 // br, bi, hb
constexpr int WS_HW   = 220;                 // 34 floats
}

__device__ __forceinline__ unsigned div9u(unsigned n)   { return __umulhi(n, 0x38E38E39u) >> 1; }
__device__ __forceinline__ unsigned div100u(unsigned n) { return __umulhi(n, 0x51EB851Fu) >> 5; }
__device__ __forceinline__ unsigned div10u(unsigned n)  { return __umulhi(n, 0x66666667u) >> 2; }

__device__ __forceinline__ unsigned pack2h(float a, float b) {
    union { __half2 h; unsigned u; } x; x.h = __floats2half2_rn(a, b); return x.u;
}
__device__ __forceinline__ __half2 bch(unsigned u) {
    union { unsigned u; __half2 h; } x; x.u = u; return x.h;
}

// Packs weights into d_ws so the main kernel can use scalar (uniform) loads:
// per tap: uint4 A = (wr,-wi) per l, uint4 B = (wi,wr) per l; then br,bi,hb; hw[34].
__global__ void prep_kernel(const float* __restrict__ wr, const float* __restrict__ wi,
                            const float* __restrict__ br, const float* __restrict__ bi,
                            const float* __restrict__ hw, const float* __restrict__ hb,
                            unsigned* __restrict__ ws)
{
    const int t = threadIdx.x;
    if (t < 27) {
        uint4* p = reinterpret_cast<uint4*>(ws + WS_WPK);
        p[2*t]   = make_uint4(pack2h(wr[3*t],   -wi[3*t]),
                              pack2h(wr[3*t+1], -wi[3*t+1]),
                              pack2h(wr[3*t+2], -wi[3*t+2]), 0u);
        p[2*t+1] = make_uint4(pack2h(wi[3*t],    wr[3*t]),
                              pack2h(wi[3*t+1],  wr[3*t+1]),
                              pack2h(wi[3*t+2],  wr[3*t+2]), 0u);
    }
    if (t < DOUT) reinterpret_cast<float*>(ws)[WS_HW + t] = hw[t];
    if (t == 63) {
        float* s = reinterpret_cast<float*>(ws);
        s[WS_SCAL] = br[0]; s[WS_SCAL+1] = bi[0]; s[WS_SCAL+2] = hb[0];
    }
}

// Coalesced stage of both channels, interleaved (xr,xi) half2 per dword.
__device__ __forceinline__ void stage(const float* __restrict__ xr, const float* __restrict__ xi,
                                      unsigned* __restrict__ s_xu, int t, unsigned g0off)
{
    #pragma unroll
    for (int it = 0; it < SITER; ++it) {
        const int C = it*NT + t;
        if (C < NCHUNK) {
            const unsigned row = div9u((unsigned)C);
            const unsigned c   = (unsigned)C - row*9u;
            const unsigned rd  = div100u(row);
            const unsigned rem = row - rd*100u;
            const unsigned re  = div10u(rem);
            const unsigned rf  = rem - re*10u;
            const unsigned goff = g0off + rd*D3 + re*D2 + rf*DIN + c*4u;
            const float4 vr = *reinterpret_cast<const float4*>(xr + goff);
            const float4 vi = *reinterpret_cast<const float4*>(xi + goff);
            unsigned* dst = s_xu + row*ROWW + c*4;
            uint2 lo, hi;
            lo.x = pack2h(vr.x, vi.x); lo.y = pack2h(vr.y, vi.y);
            hi.x = pack2h(vr.z, vi.z); hi.y = pack2h(vr.w, vi.w);
            *reinterpret_cast<uint2*>(dst)     = lo;
            *reinterpret_cast<uint2*>(dst + 2) = hi;
        }
    }
}

// One w-group's conv + epilogue. Weights/head via UNIFORM (scalar) global loads —
// zero LDS traffic for weights. All register indices compile-time.
template<int NW, int W0>
__device__ __forceinline__ float conv_group(const unsigned* __restrict__ s_xu,
                                            const uint4* __restrict__ wpk,
                                            const float* __restrict__ hws,
                                            int e, int f,
                                            float c_br, float c_bi, float hinit)
{
    constexpr int NL = (NW + 2 + 1)/2;           // b64 loads per row-window
    __half2 accr[NW], acci[NW];
    #pragma unroll
    for (int w = 0; w < NW; ++w) {
        accr[w] = __floats2half2_rn(0.f, 0.f);
        acci[w] = __floats2half2_rn(0.f, 0.f);
    }

    const int abase = (e*RF + f)*ROWW + W0;      // even dword -> 8B aligned

    #pragma unroll 1
    for (int i = 0; i < 3; ++i)
    #pragma unroll 1
    for (int j = 0; j < 3; ++j)
    {
        const unsigned* sp = s_xu + abase + (i*(RE*RF) + j*RF)*ROWW;
        const int tapb = (i*3 + j)*3;
        #pragma unroll
        for (int k = 0; k < 3; ++k)              // k*ROWW*4 folds into ds offsets
        {
            uint2 q[NL];
            #pragma unroll
            for (int m = 0; m < NL; ++m)
                q[m] = *reinterpret_cast<const uint2*>(sp + k*ROWW + 2*m);
            const __half2* win = reinterpret_cast<const __half2*>(q);

            const uint4 wa = wpk[2*(tapb + k)];      // uniform -> s_load, no LDS
            const uint4 wb = wpk[2*(tapb + k) + 1];
            #pragma unroll
            for (int l = 0; l < 3; ++l) {
                const __half2 WA = bch(l==0 ? wa.x : l==1 ? wa.y : wa.z);  // (wr, -wi)
                const __half2 WB = bch(l==0 ? wb.x : l==1 ? wb.y : wb.z);  // (wi,  wr)
                #pragma unroll
                for (int w = 0; w < NW; ++w) {
                    const __half2 x2 = win[w + l];          // (xr, xi)
                    accr[w] = __hfma2(x2, WA, accr[w]);
                    acci[w] = __hfma2(x2, WB, acci[w]);
                }
            }
        }
    }

    // fp32 epilogue: sum halves -> bias -> CReLU -> modulus -> head partial
    float h = hinit;
    #pragma unroll
    for (int w = 0; w < NW; ++w) {
        const float yr = __low2float(accr[w]) + __high2float(accr[w]) + c_br;
        const float yi = __low2float(acci[w]) + __high2float(acci[w]) + c_bi;
        const float a = fmaxf(yr, 0.f);
        const float c = fmaxf(yi, 0.f);
        const float m = sqrtf(fmaf(a, a, fmaf(c, c, 1e-12f)));
        h = fmaf(m, hws[W0 + w], h);             // uniform index -> scalar load
    }
    return h;
}

__global__ __launch_bounds__(NT)
void lasl_kernel(const float* __restrict__ xr, const float* __restrict__ xi,
                 const unsigned* __restrict__ wsu, float* __restrict__ out)
{
    __shared__ unsigned s_xu[NROWS*ROWW];        // 45.6 KB -> 3 blocks/CU

    const int t = threadIdx.x;

    // batch-per-XCD bijective swizzle: 6800 = 8 * 850
    const int bid = blockIdx.x;
    const int b   = bid & 7;
    int rem = bid >> 3;                          // 0..849
    const int d0 = rem / 25;  rem %= 25;         // 34 exact d-tiles
    const int e0 = min((rem / 5) * TE, DOUT - TE);  // overlap tiles: duplicate outputs
    const int f0 = min((rem % 5) * TF, DOUT - TF);  // write identical values

    const float* xrb = xr + (size_t)b * (size_t)(DIN*D3);
    const float* xib = xi + (size_t)b * (size_t)(DIN*D3);
    const unsigned g0off = (unsigned)((d0*DIN + e0)*DIN + f0)*DIN;

    stage(xrb, xib, s_xu, t, g0off);
    __syncthreads();

    const int f = t & 7;                         // lane = site (8f x 8e = 64)
    const int e = (t >> 3) & 7;
    const int g = t >> 6;                        // wave-uniform w-group (8 waves)

    const uint4* wpk = reinterpret_cast<const uint4*>(wsu + WS_WPK);
    const float* scal = reinterpret_cast<const float*>(wsu);
    const float* hws  = scal + WS_HW;
    const float c_br = scal[WS_SCAL], c_bi = scal[WS_SCAL+1];
    const float hini = (g == 0) ? scal[WS_SCAL+2] : 0.f;   // hb counted once

    float hp;
    if      (g == 0) hp = conv_group<6, 0>(s_xu, wpk, hws, e, f, c_br, c_bi, hini);
    else if (g == 1) hp = conv_group<4, 6>(s_xu, wpk, hws, e, f, c_br, c_bi, hini);
    else if (g == 2) hp = conv_group<4,10>(s_xu, wpk, hws, e, f, c_br, c_bi, hini);
    else if (g == 3) hp = conv_group<4,14>(s_xu, wpk, hws, e, f, c_br, c_bi, hini);
    else if (g == 4) hp = conv_group<4,18>(s_xu, wpk, hws, e, f, c_br, c_bi, hini);
    else if (g == 5) hp = conv_group<4,22>(s_xu, wpk, hws, e, f, c_br, c_bi, hini);
    else if (g == 6) hp = conv_group<4,26>(s_xu, wpk, hws, e, f, c_br, c_bi, hini);
    else             hp = conv_group<4,30>(s_xu, wpk, hws, e, f, c_br, c_bi, hini);

    // combine the 8 w-group partials (one per wave) through LDS
    __syncthreads();                             // all s_xu reads done
    float* s_red = reinterpret_cast<float*>(s_xu);
    s_red[t] = hp;
    __syncthreads();

    if (g == 0) {
        const int eg = e0 + e, fg = f0 + f;      // always < 34 (overlap tiling)
        float htot = hp;
        #pragma unroll
        for (int gg = 1; gg < 8; ++gg) htot += s_red[t + 64*gg];
        out[(((size_t)b*DOUT + d0)*DOUT + eg)*DOUT + fg] = 1.f / (1.f + __expf(-htot));
    }
}

extern "C" void kernel_launch(void* const* d_in, const int* in_sizes, int n_in,
                              void* d_out, int out_size, void* d_ws, size_t ws_size,
                              hipStream_t stream)
{
    const float* xr = (const float*)d_in[0];
    const float* xi = (const float*)d_in[1];
    const float* wr = (const float*)d_in[2];
    const float* wi = (const float*)d_in[3];
    const float* br = (const float*)d_in[4];
    const float* bi = (const float*)d_in[5];
    const float* hw = (const float*)d_in[6];
    const float* hb = (const float*)d_in[7];
    float* out = (float*)d_out;
    unsigned* ws = (unsigned*)d_ws;

    prep_kernel<<<1, 64, 0, stream>>>(wr, wi, br, bi, hw, hb, ws);
    lasl_kernel<<<NBLOCKS, NT, 0, stream>>>(xr, xi, ws, out);
}